// Round 2
// baseline (631.913 us; speedup 1.0000x reference)
//
#include <hip/hip_runtime.h>

// Problem constants (match reference)
constexpr int B  = 2;
constexpr int N  = 18432;          // divisible by 64 -> no tail lanes
constexpr int C  = 1024;
constexpr int GR = 40;
constexpr int NV = GR * GR * GR;   // 64000
constexpr int BNV = B * NV;        // 128000
constexpr int ZERO_VOX = 820;      // voxel of masked-to-origin points: 20 + 40*20

constexpr int VPW = 16;            // voxels per wave in the gather
constexpr int GATHER_BLOCKS = BNV / (4 * VPW);   // 4 waves/block -> 2000 blocks

typedef float v4f __attribute__((ext_vector_type(4)));

// ---------------------------------------------------------------------------
// Kernel 1: per-point voxel id + validity; wave-aggregated hot atomics;
// valid points pushed onto a per-voxel linked list (head holds i+1, 0=empty).
// ---------------------------------------------------------------------------
__global__ void points_kernel(const float* __restrict__ xyz,
                              int* __restrict__ cntAll,
                              int* __restrict__ head,
                              int* __restrict__ nxt,
                              int* __restrict__ bmax) {
    int i = blockIdx.x * blockDim.x + threadIdx.x;   // [0, B*N), no tail
    int b = i / N;                                   // wave-uniform (N % 64 == 0)
    int lane = threadIdx.x & 63;

    float x = xyz[3 * i + 0];
    float y = xyz[3 * i + 1];
    float z = xyz[3 * i + 2];

    bool valid = (x > -0.5f) && (x < 0.5f) &&
                 (y > -0.5f) && (y < 0.5f) &&
                 (z >  0.0f) && (z < 1.0f);

    // reference masks invalid xyz to 0 BEFORE voxelization
    float xm = valid ? x : 0.0f;
    float ym = valid ? y : 0.0f;
    float zm = valid ? z : 0.0f;

    int ix = min(max((int)floorf((xm + 0.5f) / 0.025f), 0), GR - 1);
    int iy = min(max((int)floorf((ym + 0.5f) / 0.025f), 0), GR - 1);
    int iz = min(max((int)floorf(zm / 0.025f), 0), GR - 1);
    int v = ix + GR * iy + GR * GR * iz;             // invalid -> ZERO_VOX

    // per-batch max voxel id: shfl-reduce, one atomic per wave
    int m = v;
    #pragma unroll
    for (int o = 32; o >= 1; o >>= 1)
        m = max(m, __shfl_xor(m, o, 64));
    if (lane == 0) atomicMax(&bmax[b], m);

    // denominator counts ALL points; invalid lanes all hit ZERO_VOX -> one
    // aggregated atomic per wave instead of ~27 serialized same-address adds
    unsigned long long vb = __ballot(valid);
    int nInv = 64 - __popcll(vb);
    if (lane == 0 && nInv > 0) atomicAdd(&cntAll[b * NV + ZERO_VOX], nInv);

    if (valid) {
        int g = b * NV + v;
        atomicAdd(&cntAll[g], 1);
        nxt[i] = atomicExch(&head[g], i + 1);        // push onto voxel list
    }
}

// ---------------------------------------------------------------------------
// Kernel 2: dense gather, one WAVE per voxel row (4 KB), VPW=16 voxels per
// wave chunked. Writes every output byte exactly once (zeros for empty
// voxels fused into the same nontemporal store stream -> no separate memset,
// no double-write). Chunk metadata (16 heads + 16 counts) is fetched in ONE
// coalesced load and shfl-broadcast, so head-load latency is paid once per
// 16 voxels instead of once per voxel (round-0's limiter).
// ---------------------------------------------------------------------------
__global__ __launch_bounds__(256) void gather_dense(const float* __restrict__ feats,
                                                    const int* __restrict__ head,
                                                    const int* __restrict__ nxt,
                                                    const int* __restrict__ cntAll,
                                                    float* __restrict__ out) {
    int waveId = blockIdx.x * (blockDim.x >> 6) + (threadIdx.x >> 6);
    int lane   = threadIdx.x & 63;
    int gBase  = waveId * VPW;                       // 2000*4*16 == BNV exactly
    if (gBase >= BNV) return;

    // lanes 0..15 fetch the chunk's head pointers, lanes 16..31 the counts
    int hv = 0;
    if (lane < VPW)                 hv = head[gBase + lane];
    int cv = 0;
    if (lane >= VPW && lane < 2*VPW) cv = cntAll[gBase + (lane - VPW)];

    for (int k = 0; k < VPW; ++k) {
        int p = __shfl(hv, k, 64);                   // wave-uniform
        v4f a0{0,0,0,0}, a1{0,0,0,0}, a2{0,0,0,0}, a3{0,0,0,0};
        if (p) {                                     // uniform branch
            float inv = 1.0f / (float)__shfl(cv, VPW + k, 64);
            while (p) {
                int pn = nxt[p - 1];                 // prefetch next link
                const v4f* src = (const v4f*)(feats + (size_t)(p - 1) * C);
                a0 += src[lane];                     // 4 x fully-contiguous 1KB
                a1 += src[lane + 64];
                a2 += src[lane + 128];
                a3 += src[lane + 192];
                p = pn;
            }
            a0 *= inv; a1 *= inv; a2 *= inv; a3 *= inv;
        }
        v4f* dst = (v4f*)(out + (size_t)(gBase + k) * C);
        __builtin_nontemporal_store(a0, dst + lane);
        __builtin_nontemporal_store(a1, dst + lane + 64);
        __builtin_nontemporal_store(a2, dst + lane + 128);
        __builtin_nontemporal_store(a3, dst + lane + 192);
    }
}

// ---------------------------------------------------------------------------
// Kernel 3: batch_offset = cumsum(max voxel id per batch + 1), as float
// ---------------------------------------------------------------------------
__global__ void offs_out_kernel(const int* __restrict__ bmax,
                                float* __restrict__ out_offs) {
    if (threadIdx.x == 0 && blockIdx.x == 0) {
        int m0 = bmax[0];
        int m1 = bmax[1];
        out_offs[0] = (float)(m0 + 1);
        out_offs[1] = (float)(m0 + 1 + m1 + 1);
    }
}

// ---------------------------------------------------------------------------
extern "C" void kernel_launch(void* const* d_in, const int* in_sizes, int n_in,
                              void* d_out, int out_size, void* d_ws, size_t ws_size,
                              hipStream_t stream) {
    const float* feats = (const float*)d_in[0];   // (B, N, C) fp32
    const float* xyz   = (const float*)d_in[1];   // (B, N, 3) fp32
    float* out = (float*)d_out;                   // pooled (B,NV,C) ++ batch_offset (B,)

    // workspace layout (int32): zeroed region first, one memset covers it
    int* w      = (int*)d_ws;
    int* cntAll = w;                 // BNV   (zeroed)
    int* head   = cntAll + BNV;      // BNV   (zeroed; 0 = empty list)
    int* bmax   = head + BNV;        // B     (zeroed)
    int* nxt    = bmax + B;          // B*N   (no init needed)

    hipMemsetAsync(cntAll, 0, (size_t)(2 * BNV + B) * sizeof(int), stream);

    // 64-thread blocks: 576 WGs spread across 256 CUs
    points_kernel<<<(B * N) / 64, 64, 0, stream>>>(xyz, cntAll, head, nxt, bmax);

    // 2000 blocks x 4 waves, one wave per 4KB voxel row, 16 rows per wave
    gather_dense<<<GATHER_BLOCKS, 256, 0, stream>>>(feats, head, nxt, cntAll, out);

    offs_out_kernel<<<1, 64, 0, stream>>>(bmax, out + (size_t)B * NV * C);
}

// Round 3
// 604.197 us; speedup vs baseline: 1.0459x; 1.0459x over previous
//
#include <hip/hip_runtime.h>

// Problem constants (match reference)
constexpr int B  = 2;
constexpr int N  = 18432;          // divisible by 256 -> no tail lanes
constexpr int C  = 1024;
constexpr int GR = 40;
constexpr int NV = GR * GR * GR;   // 64000
constexpr int BNV = B * NV;        // 128000
constexpr int ZERO_VOX = 820;      // voxel of masked-to-origin points: 20 + 40*20

typedef float v4f __attribute__((ext_vector_type(4)));

// Per-voxel metadata interleaved in one 8B struct: .x = count, .y = list head
// (head holds i+1, 0 = empty). One cacheline for both -> gather does a single
// uniform 8B load instead of two scalar loads 512 KB apart.
// ---------------------------------------------------------------------------
// Kernel 1: per-point voxel id + validity; wave-aggregated hot atomics;
// valid points pushed onto a per-voxel linked list.
// ---------------------------------------------------------------------------
__global__ void points_kernel(const float* __restrict__ xyz,
                              int2* __restrict__ hcAll,
                              int* __restrict__ nxt,
                              int* __restrict__ bmax) {
    int i = blockIdx.x * blockDim.x + threadIdx.x;   // [0, B*N), no tail
    int b = i / N;                                   // wave-uniform (N % 64 == 0)
    int lane = threadIdx.x & 63;

    float x = xyz[3 * i + 0];
    float y = xyz[3 * i + 1];
    float z = xyz[3 * i + 2];

    bool valid = (x > -0.5f) && (x < 0.5f) &&
                 (y > -0.5f) && (y < 0.5f) &&
                 (z >  0.0f) && (z < 1.0f);

    // reference masks invalid xyz to 0 BEFORE voxelization
    float xm = valid ? x : 0.0f;
    float ym = valid ? y : 0.0f;
    float zm = valid ? z : 0.0f;

    int ix = min(max((int)floorf((xm + 0.5f) / 0.025f), 0), GR - 1);
    int iy = min(max((int)floorf((ym + 0.5f) / 0.025f), 0), GR - 1);
    int iz = min(max((int)floorf(zm / 0.025f), 0), GR - 1);
    int v = ix + GR * iy + GR * GR * iz;             // invalid -> ZERO_VOX

    // per-batch max voxel id: shfl-reduce, one atomic per wave
    int m = v;
    #pragma unroll
    for (int o = 32; o >= 1; o >>= 1)
        m = max(m, __shfl_xor(m, o, 64));
    if (lane == 0) atomicMax(&bmax[b], m);

    // denominator counts ALL points; invalid lanes all hit ZERO_VOX -> one
    // aggregated atomic per wave instead of ~27 serialized same-address adds
    unsigned long long vb = __ballot(valid);
    int nInv = 64 - __popcll(vb);
    if (lane == 0 && nInv > 0) atomicAdd(&hcAll[b * NV + ZERO_VOX].x, nInv);

    if (valid) {
        int g = b * NV + v;
        atomicAdd(&hcAll[g].x, 1);                   // count
        nxt[i] = atomicExch(&hcAll[g].y, i + 1);     // push onto voxel list
    }
}

// ---------------------------------------------------------------------------
// Kernel 2: dense gather — the round-0 structure (best measured: ~96 us,
// ~6 TB/s effective). One block (256 threads, one float4 each) per output
// voxel row. Walk the (short, avg ~1.09) point list, sum, multiply by 1/cnt,
// single nontemporal 16B store per thread. Empty voxels write zeros -> every
// output byte written exactly once, no separate memset.
// Metadata is ONE uniform 8B load per block (int2 {cnt, head}).
// ---------------------------------------------------------------------------
__global__ __launch_bounds__(256) void gather_kernel(const float* __restrict__ feats,
                                                     const int2* __restrict__ hcAll,
                                                     const int* __restrict__ nxt,
                                                     float* __restrict__ out) {
    int g = blockIdx.x;                              // [0, B*NV)
    int2 hc = hcAll[g];                              // uniform -> s_load_dwordx2
    int p = hc.y;
    float inv = 1.0f / (float)max(hc.x, 1);

    v4f acc = {0.0f, 0.0f, 0.0f, 0.0f};
    while (p) {
        int pn = nxt[p - 1];                         // prefetch next link
        const v4f* src = (const v4f*)(feats + (size_t)(p - 1) * C);
        acc += src[threadIdx.x];
        p = pn;
    }
    acc *= inv;
    v4f* dst = (v4f*)(out + (size_t)g * C);
    __builtin_nontemporal_store(acc, dst + threadIdx.x);
}

// ---------------------------------------------------------------------------
// Kernel 3: batch_offset = cumsum(max voxel id per batch + 1), as float
// ---------------------------------------------------------------------------
__global__ void offs_out_kernel(const int* __restrict__ bmax,
                                float* __restrict__ out_offs) {
    if (threadIdx.x == 0 && blockIdx.x == 0) {
        int m0 = bmax[0];
        int m1 = bmax[1];
        out_offs[0] = (float)(m0 + 1);
        out_offs[1] = (float)(m0 + 1 + m1 + 1);
    }
}

// ---------------------------------------------------------------------------
extern "C" void kernel_launch(void* const* d_in, const int* in_sizes, int n_in,
                              void* d_out, int out_size, void* d_ws, size_t ws_size,
                              hipStream_t stream) {
    const float* feats = (const float*)d_in[0];   // (B, N, C) fp32
    const float* xyz   = (const float*)d_in[1];   // (B, N, 3) fp32
    float* out = (float*)d_out;                   // pooled (B,NV,C) ++ batch_offset (B,)

    // workspace layout: zeroed region first, one memset covers it
    int2* hcAll = (int2*)d_ws;             // BNV int2 {cnt, head} (zeroed)
    int*  bmax  = (int*)(hcAll + BNV);     // B                    (zeroed)
    int*  nxt   = bmax + B;                // B*N                  (no init needed)

    hipMemsetAsync(hcAll, 0, (size_t)(2 * BNV + B) * sizeof(int), stream);

    points_kernel<<<(B * N) / 256, 256, 0, stream>>>(xyz, hcAll, nxt, bmax);
    gather_kernel<<<BNV, 256, 0, stream>>>(feats, hcAll, nxt, out);
    offs_out_kernel<<<1, 64, 0, stream>>>(bmax, out + (size_t)B * NV * C);
}